// Round 1
// baseline (2235.499 us; speedup 1.0000x reference)
//
#include <hip/hip_runtime.h>

#define NB 8
#define NN 8192
#define NC 32
#define NPOINT 1024
#define NSAMPLE 32

// Exact round-to-nearest distance, no fma contraction: matches numpy
// ((dx*dx + dy*dy) + dz*dz) bitwise.
__device__ __forceinline__ float d2_exact(float ax, float ay, float az,
                                          float bx, float by, float bz) {
    float dx = __fsub_rn(ax, bx);
    float dy = __fsub_rn(ay, by);
    float dz = __fsub_rn(az, bz);
    return __fadd_rn(__fadd_rn(__fmul_rn(dx, dx), __fmul_rn(dy, dy)),
                     __fmul_rn(dz, dz));
}

// ---------------------------------------------------------------------------
// Kernel 1: furthest point sampling, one block per batch.
// 512 threads, 16 points/thread held in registers. One __syncthreads per
// iteration (parity double-buffered reduction slots remove the WAR hazard).
// ---------------------------------------------------------------------------
#define FPS_T 512
#define FPS_K (NN / FPS_T)   // 16

__global__ __launch_bounds__(FPS_T) void fps_kernel(
    const float* __restrict__ xyz, const float* __restrict__ normal,
    float* __restrict__ out_xyz, float* __restrict__ out_normal) {
    const int b = blockIdx.x;
    const float* bx = xyz + (size_t)b * NN * 3;
    const int tid = threadIdx.x;
    const int lane = tid & 63;
    const int wave = tid >> 6;   // 0..7

    __shared__ float redv[2][8], redx[2][8], redy[2][8], redz[2][8];
    __shared__ int redi[2][8];
    __shared__ int sel_hist[NPOINT];

    float px[FPS_K], py[FPS_K], pz[FPS_K], dist[FPS_K];
#pragma unroll
    for (int k = 0; k < FPS_K; ++k) {
        int p = tid + k * FPS_T;
        px[k] = bx[p * 3 + 0];
        py[k] = bx[p * 3 + 1];
        pz[k] = bx[p * 3 + 2];
        dist[k] = 1e10f;
    }

    int last = 0;
    float lx = bx[0], ly = bx[1], lz = bx[2];

    for (int it = 0; it < NPOINT; ++it) {
        const int par = it & 1;
        if (tid == 0) sel_hist[it] = last;

        // update dists with last-selected point; track per-thread argmax
        float bv = -1.0f;
        int bi = 0x7fffffff;
#pragma unroll
        for (int k = 0; k < FPS_K; ++k) {
            float d = d2_exact(px[k], py[k], pz[k], lx, ly, lz);
            float nd = fminf(dist[k], d);
            dist[k] = nd;
            if (nd > bv) { bv = nd; bi = tid + k * FPS_T; }  // ascending index
        }
        // wave-level reduce: max value, tie -> smaller index
#pragma unroll
        for (int off = 32; off >= 1; off >>= 1) {
            float ov = __shfl_xor(bv, off);
            int oi = __shfl_xor(bi, off);
            if (ov > bv || (ov == bv && oi < bi)) { bv = ov; bi = oi; }
        }
        // owner lane (the one holding the winning point) publishes v,i,coords
        if (tid == (bi & (FPS_T - 1))) {
            int k = bi >> 9;   // log2(FPS_T)
            float sx = px[0], sy = py[0], sz = pz[0];
#pragma unroll
            for (int kk = 1; kk < FPS_K; ++kk) {
                if (k == kk) { sx = px[kk]; sy = py[kk]; sz = pz[kk]; }
            }
            redv[par][wave] = bv; redi[par][wave] = bi;
            redx[par][wave] = sx; redy[par][wave] = sy; redz[par][wave] = sz;
        }
        __syncthreads();
        // cross-wave reduce (8 slots), replicated in every wave
        float v = (lane < 8) ? redv[par][lane] : -1.0f;
        int i2 = (lane < 8) ? redi[par][lane] : 0x7fffffff;
        int sl = lane;
#pragma unroll
        for (int off = 4; off >= 1; off >>= 1) {
            float ov = __shfl_xor(v, off);
            int oi = __shfl_xor(i2, off);
            int os = __shfl_xor(sl, off);
            if (ov > v || (ov == v && oi < i2)) { v = ov; i2 = oi; sl = os; }
        }
        int wsl = __shfl(sl, 0);
        last = __shfl(i2, 0);
        lx = redx[par][wsl]; ly = redy[par][wsl]; lz = redz[par][wsl];
    }
    __syncthreads();

    // gather new_xyz / new_normal
    const float* bn = normal + (size_t)b * NN * 3;
    for (int t = tid; t < NPOINT; t += FPS_T) {
        int i = sel_hist[t];
        size_t o = ((size_t)b * NPOINT + t) * 3;
        out_xyz[o + 0] = bx[i * 3 + 0];
        out_xyz[o + 1] = bx[i * 3 + 1];
        out_xyz[o + 2] = bx[i * 3 + 2];
        out_normal[o + 0] = bn[i * 3 + 0];
        out_normal[o + 1] = bn[i * 3 + 1];
        out_normal[o + 2] = bn[i * 3 + 2];
    }
}

// ---------------------------------------------------------------------------
// Kernel 2: ball query + gather + 3-layer MLP + maxpool, one wave per
// centroid, 2 waves (128 threads) per block (static LDS < 64 KB).
// ---------------------------------------------------------------------------
#define K2_WAVES 2
#define XS 37   // X row stride (35 cols + pad): banks distinct across sg
#define HS 65   // H row stride (64 cols + pad): banks distinct across sg

__global__ __launch_bounds__(64 * K2_WAVES) void group_mlp_kernel(
    const float* __restrict__ xyz, const float* __restrict__ features,
    const float* __restrict__ w1, const float* __restrict__ b1,
    const float* __restrict__ w2, const float* __restrict__ b2,
    const float* __restrict__ w3, const float* __restrict__ b3,
    const float* __restrict__ new_xyz, float* __restrict__ out_feat) {
    const int wave = threadIdx.x >> 6;
    const int lane = threadIdx.x & 63;
    const int g = blockIdx.x * K2_WAVES + wave;   // centroid id, 0..8191
    const int b = g >> 10;
    const int p = g & 1023;
    const float* bxp = xyz + (size_t)b * NN * 3;
    const float* bfp = features + (size_t)b * NN * NC;

    __shared__ int sel_s[K2_WAVES][NSAMPLE];
    __shared__ float bufA[K2_WAVES][32 * HS];   // X (stride XS) then H2 (stride HS)
    __shared__ float bufB[K2_WAVES][32 * HS];   // H1

    const float cx = new_xyz[(size_t)g * 3 + 0];
    const float cy = new_xyz[(size_t)g * 3 + 1];
    const float cz = new_xyz[(size_t)g * 3 + 2];

    // ---- ball query: first NSAMPLE hits in ascending index order ----------
    int have = 0;
    for (int ch = 0; ch < NN / 64 && have < NSAMPLE; ++ch) {
        int j = ch * 64 + lane;
        float x = bxp[j * 3 + 0], y = bxp[j * 3 + 1], z = bxp[j * 3 + 2];
        float d2 = d2_exact(x, y, z, cx, cy, cz);
        bool hit = d2 < 0.04f;   // strict f32 compare (NEP50 semantics)
        unsigned long long m = __ballot(hit);
        int pos = have + __popcll(m & ((1ull << lane) - 1ull));
        if (hit && pos < NSAMPLE) sel_s[wave][pos] = j;
        have += __popcll(m);
    }
    __syncthreads();
    int nsel = have < NSAMPLE ? have : NSAMPLE;
    int first = sel_s[wave][0];   // centroid itself always hits -> nsel >= 1
    if (lane < NSAMPLE && lane >= nsel) sel_s[wave][lane] = first;
    __syncthreads();

    // ---- gather X = [rel_xyz(3) | features(32)] into LDS ------------------
    {
        int s = lane >> 1, h = lane & 1;
        int row = sel_s[wave][s];
        float* X = &bufA[wave][0];
        const float* fr = bfp + (size_t)row * NC + h * 16;
#pragma unroll
        for (int q = 0; q < 4; ++q) {
            float4 v = *(const float4*)(fr + q * 4);
            int base = s * XS + 3 + h * 16 + q * 4;
            X[base + 0] = v.x; X[base + 1] = v.y;
            X[base + 2] = v.z; X[base + 3] = v.w;
        }
        if (h == 0) {
            X[s * XS + 0] = __fsub_rn(bxp[row * 3 + 0], cx);
            X[s * XS + 1] = __fsub_rn(bxp[row * 3 + 1], cy);
            X[s * XS + 2] = __fsub_rn(bxp[row * 3 + 2], cz);
        }
    }
    __syncthreads();

    const int sg = lane >> 3;   // 0..7 -> samples sg*4 .. sg*4+3
    const int og = lane & 7;    // output-channel group

    // ---- layer 1: 35 -> 64 ------------------------------------------------
    {
        float acc[4][8];
#pragma unroll
        for (int j = 0; j < 4; ++j)
#pragma unroll
            for (int o = 0; o < 8; ++o) acc[j][o] = 0.f;
        const float* X = &bufA[wave][0];
        for (int c = 0; c < 35; ++c) {
            float xv[4];
#pragma unroll
            for (int j = 0; j < 4; ++j) xv[j] = X[(sg * 4 + j) * XS + c];
            const float* wr = w1 + c * 64 + og * 8;
            float4 wa = *(const float4*)(wr);
            float4 wb = *(const float4*)(wr + 4);
            float w8[8] = {wa.x, wa.y, wa.z, wa.w, wb.x, wb.y, wb.z, wb.w};
#pragma unroll
            for (int j = 0; j < 4; ++j)
#pragma unroll
                for (int o = 0; o < 8; ++o) acc[j][o] += xv[j] * w8[o];
        }
        float4 ba = *(const float4*)(b1 + og * 8);
        float4 bb = *(const float4*)(b1 + og * 8 + 4);
        float bias[8] = {ba.x, ba.y, ba.z, ba.w, bb.x, bb.y, bb.z, bb.w};
        float* H = &bufB[wave][0];
#pragma unroll
        for (int j = 0; j < 4; ++j)
#pragma unroll
            for (int o = 0; o < 8; ++o)
                H[(sg * 4 + j) * HS + og * 8 + o] = fmaxf(acc[j][o] + bias[o], 0.f);
    }
    __syncthreads();

    // ---- layer 2: 64 -> 64 ------------------------------------------------
    {
        float acc[4][8];
#pragma unroll
        for (int j = 0; j < 4; ++j)
#pragma unroll
            for (int o = 0; o < 8; ++o) acc[j][o] = 0.f;
        const float* H = &bufB[wave][0];
        for (int c = 0; c < 64; ++c) {
            float xv[4];
#pragma unroll
            for (int j = 0; j < 4; ++j) xv[j] = H[(sg * 4 + j) * HS + c];
            const float* wr = w2 + c * 64 + og * 8;
            float4 wa = *(const float4*)(wr);
            float4 wb = *(const float4*)(wr + 4);
            float w8[8] = {wa.x, wa.y, wa.z, wa.w, wb.x, wb.y, wb.z, wb.w};
#pragma unroll
            for (int j = 0; j < 4; ++j)
#pragma unroll
                for (int o = 0; o < 8; ++o) acc[j][o] += xv[j] * w8[o];
        }
        float4 ba = *(const float4*)(b2 + og * 8);
        float4 bb = *(const float4*)(b2 + og * 8 + 4);
        float bias[8] = {ba.x, ba.y, ba.z, ba.w, bb.x, bb.y, bb.z, bb.w};
        float* H2 = &bufA[wave][0];
#pragma unroll
        for (int j = 0; j < 4; ++j)
#pragma unroll
            for (int o = 0; o < 8; ++o)
                H2[(sg * 4 + j) * HS + og * 8 + o] = fmaxf(acc[j][o] + bias[o], 0.f);
    }
    __syncthreads();

    // ---- layer 3: 64 -> 128, maxpool over 32 samples ----------------------
    {
        float acc[4][16];
#pragma unroll
        for (int j = 0; j < 4; ++j)
#pragma unroll
            for (int o = 0; o < 16; ++o) acc[j][o] = 0.f;
        const float* H = &bufA[wave][0];
        for (int c = 0; c < 64; ++c) {
            float xv[4];
#pragma unroll
            for (int j = 0; j < 4; ++j) xv[j] = H[(sg * 4 + j) * HS + c];
            const float* wr = w3 + c * 128 + og * 16;
            float4 wq[4];
#pragma unroll
            for (int q = 0; q < 4; ++q) wq[q] = *(const float4*)(wr + q * 4);
            float w16[16] = {wq[0].x, wq[0].y, wq[0].z, wq[0].w,
                             wq[1].x, wq[1].y, wq[1].z, wq[1].w,
                             wq[2].x, wq[2].y, wq[2].z, wq[2].w,
                             wq[3].x, wq[3].y, wq[3].z, wq[3].w};
#pragma unroll
            for (int j = 0; j < 4; ++j)
#pragma unroll
                for (int o = 0; o < 16; ++o) acc[j][o] += xv[j] * w16[o];
        }
        // maxpool over the 4 local samples, then across sg via shuffles.
        float m[16];
#pragma unroll
        for (int o = 0; o < 16; ++o) {
            float t0 = fmaxf(acc[0][o], acc[1][o]);
            float t1 = fmaxf(acc[2][o], acc[3][o]);
            m[o] = fmaxf(t0, t1);
        }
#pragma unroll
        for (int off = 8; off <= 32; off <<= 1)
#pragma unroll
            for (int o = 0; o < 16; ++o) m[o] = fmaxf(m[o], __shfl_xor(m[o], off));
        // bias after max (exact: rn add is monotone), then relu, store
        if (sg == 0) {
            float4 bq[4];
#pragma unroll
            for (int q = 0; q < 4; ++q) bq[q] = *(const float4*)(b3 + og * 16 + q * 4);
            float bias[16] = {bq[0].x, bq[0].y, bq[0].z, bq[0].w,
                              bq[1].x, bq[1].y, bq[1].z, bq[1].w,
                              bq[2].x, bq[2].y, bq[2].z, bq[2].w,
                              bq[3].x, bq[3].y, bq[3].z, bq[3].w};
#pragma unroll
            for (int o = 0; o < 16; ++o) {
                float v = fmaxf(m[o] + bias[o], 0.f);
                out_feat[((size_t)b * 128 + og * 16 + o) * NPOINT + p] = v;
            }
        }
    }
}

// ---------------------------------------------------------------------------
extern "C" void kernel_launch(void* const* d_in, const int* in_sizes, int n_in,
                              void* d_out, int out_size, void* d_ws, size_t ws_size,
                              hipStream_t stream) {
    const float* xyz      = (const float*)d_in[0];
    const float* normal   = (const float*)d_in[1];
    const float* features = (const float*)d_in[2];
    const float* w1 = (const float*)d_in[3];
    const float* b1 = (const float*)d_in[4];
    const float* w2 = (const float*)d_in[5];
    const float* b2 = (const float*)d_in[6];
    const float* w3 = (const float*)d_in[7];
    const float* b3 = (const float*)d_in[8];

    float* out        = (float*)d_out;
    float* out_xyz    = out;                       // (8,1024,3)
    float* out_normal = out + NB * NPOINT * 3;     // (8,1024,3)
    float* out_feat   = out + 2 * NB * NPOINT * 3; // (8,128,1024)

    hipLaunchKernelGGL(fps_kernel, dim3(NB), dim3(FPS_T), 0, stream,
                       xyz, normal, out_xyz, out_normal);
    hipLaunchKernelGGL(group_mlp_kernel, dim3(NB * NPOINT / K2_WAVES),
                       dim3(64 * K2_WAVES), 0, stream,
                       xyz, features, w1, b1, w2, b2, w3, b3, out_xyz, out_feat);
}

// Round 2
// 1191.889 us; speedup vs baseline: 1.8756x; 1.8756x over previous
//
#include <hip/hip_runtime.h>

#define NB 8
#define NN 8192
#define NC 32
#define NPOINT 1024
#define NSAMPLE 32

// Exact round-to-nearest distance, no fma contraction: matches numpy
// ((dx*dx + dy*dy) + dz*dz) bitwise.
__device__ __forceinline__ float d2_exact(float ax, float ay, float az,
                                          float bx, float by, float bz) {
    float dx = __fsub_rn(ax, bx);
    float dy = __fsub_rn(ay, by);
    float dz = __fsub_rn(az, bz);
    return __fadd_rn(__fadd_rn(__fmul_rn(dx, dx), __fmul_rn(dy, dy)),
                     __fmul_rn(dz, dz));
}

// ---------------------------------------------------------------------------
// Kernel 1: furthest point sampling, one block per batch, 256 threads
// (4 waves, 1 wave/SIMD), 32 points/thread in registers.
//
// Argmax strategy: key = (f32_bits(dist) << 32) | ~p. dist >= 0 so bits are
// monotone; max(key) = max dist with ties -> min p (numpy first-occurrence).
// Wave reduce via DPP (VALU speed, no LDS-pipe bpermute); cross-wave via 4
// LDS slots + ONE barrier/iter (parity double-buffer); winner coords via
// uniform scalar global load (no owner-publish branch, no extra barrier).
// ---------------------------------------------------------------------------
#define FPS_T 256
#define FPS_K (NN / FPS_T)   // 32

__device__ __forceinline__ unsigned long long kmax64(unsigned long long a,
                                                     unsigned long long b) {
    return a > b ? a : b;
}

template <int CTRL, int RM>
__device__ __forceinline__ unsigned long long dpp_k(unsigned long long k) {
    unsigned hi = (unsigned)__builtin_amdgcn_update_dpp(
        0, (int)(k >> 32), CTRL, RM, 0xf, true);
    unsigned lo = (unsigned)__builtin_amdgcn_update_dpp(
        0, (int)(k & 0xffffffffULL), CTRL, RM, 0xf, true);
    return ((unsigned long long)hi << 32) | lo;
}

__global__ __launch_bounds__(FPS_T) void fps_kernel(
    const float* __restrict__ xyz, const float* __restrict__ normal,
    float* __restrict__ out_xyz, float* __restrict__ out_normal) {
    const int b = blockIdx.x;
    const float* bx = xyz + (size_t)b * NN * 3;
    const int tid = threadIdx.x;
    const int lane = tid & 63;
    const int wave = tid >> 6;   // 0..3

    __shared__ unsigned long long redk[2][4];
    __shared__ int sel_hist[NPOINT];

    float px[FPS_K], py[FPS_K], pz[FPS_K], dist[FPS_K];
#pragma unroll
    for (int k = 0; k < FPS_K; ++k) {
        int p = tid + k * FPS_T;
        px[k] = bx[p * 3 + 0];
        py[k] = bx[p * 3 + 1];
        pz[k] = bx[p * 3 + 2];
        dist[k] = 1e10f;
    }

    int cur = 0;
    float lx = bx[0], ly = bx[1], lz = bx[2];

    for (int it = 0; it < NPOINT; ++it) {
        const int par = it & 1;
        if (tid == 0) sel_hist[it] = cur;

        // update dists with current point; track per-thread argmax as k-index
        float bv = -1.0f;
        int bk = 0;
#pragma unroll
        for (int k = 0; k < FPS_K; ++k) {
            float d = d2_exact(px[k], py[k], pz[k], lx, ly, lz);
            float nd = fminf(dist[k], d);
            dist[k] = nd;
            bool gt = nd > bv;          // strict >: keeps lowest p on ties
            bv = gt ? nd : bv;
            bk = gt ? k : bk;           // k is an inline const per unroll step
        }
        int bp = tid + (bk << 8);       // global point index (FPS_T == 256)
        unsigned long long key =
            ((unsigned long long)__float_as_uint(bv) << 32) |
            (unsigned)(~bp);

        // wave-wide max via DPP: row_shr 1/2/4/8, bcast15, bcast31.
        // Zero-fill is safe: key 0 => dist +0.0, ~p=0 -> never beats a real key.
        key = kmax64(key, dpp_k<0x111, 0xf>(key));
        key = kmax64(key, dpp_k<0x112, 0xf>(key));
        key = kmax64(key, dpp_k<0x114, 0xf>(key));
        key = kmax64(key, dpp_k<0x118, 0xf>(key));
        key = kmax64(key, dpp_k<0x142, 0xa>(key));
        key = kmax64(key, dpp_k<0x143, 0xc>(key));
        // lane 63 holds the wave max
        if (lane == 63) redk[par][wave] = key;
        __syncthreads();

        unsigned long long g =
            kmax64(kmax64(redk[par][0], redk[par][1]),
                   kmax64(redk[par][2], redk[par][3]));
        int p = (int)(~(unsigned)(g & 0xffffffffULL));
        p = __builtin_amdgcn_readfirstlane(p);   // uniform -> scalar loads
        const float* lp = bx + 3 * (size_t)p;
        lx = lp[0]; ly = lp[1]; lz = lp[2];
        cur = p;
    }
    __syncthreads();

    // gather new_xyz / new_normal
    const float* bn = normal + (size_t)b * NN * 3;
    for (int t = tid; t < NPOINT; t += FPS_T) {
        int i = sel_hist[t];
        size_t o = ((size_t)b * NPOINT + t) * 3;
        out_xyz[o + 0] = bx[i * 3 + 0];
        out_xyz[o + 1] = bx[i * 3 + 1];
        out_xyz[o + 2] = bx[i * 3 + 2];
        out_normal[o + 0] = bn[i * 3 + 0];
        out_normal[o + 1] = bn[i * 3 + 1];
        out_normal[o + 2] = bn[i * 3 + 2];
    }
}

// ---------------------------------------------------------------------------
// Kernel 2: ball query + gather + 3-layer MLP + maxpool, one wave per
// centroid, 2 waves (128 threads) per block (static LDS < 64 KB).
// ---------------------------------------------------------------------------
#define K2_WAVES 2
#define XS 37   // X row stride (35 cols + pad)
#define HS 65   // H row stride (64 cols + pad)

__global__ __launch_bounds__(64 * K2_WAVES) void group_mlp_kernel(
    const float* __restrict__ xyz, const float* __restrict__ features,
    const float* __restrict__ w1, const float* __restrict__ b1,
    const float* __restrict__ w2, const float* __restrict__ b2,
    const float* __restrict__ w3, const float* __restrict__ b3,
    const float* __restrict__ new_xyz, float* __restrict__ out_feat) {
    const int wave = threadIdx.x >> 6;
    const int lane = threadIdx.x & 63;
    const int g = blockIdx.x * K2_WAVES + wave;   // centroid id, 0..8191
    const int b = g >> 10;
    const int p = g & 1023;
    const float* bxp = xyz + (size_t)b * NN * 3;
    const float* bfp = features + (size_t)b * NN * NC;

    __shared__ int sel_s[K2_WAVES][NSAMPLE];
    __shared__ float bufA[K2_WAVES][32 * HS];   // X (stride XS) then H2 (stride HS)
    __shared__ float bufB[K2_WAVES][32 * HS];   // H1

    const float cx = new_xyz[(size_t)g * 3 + 0];
    const float cy = new_xyz[(size_t)g * 3 + 1];
    const float cz = new_xyz[(size_t)g * 3 + 2];

    // ---- ball query: first NSAMPLE hits in ascending index order ----------
    int have = 0;
    for (int ch = 0; ch < NN / 64 && have < NSAMPLE; ++ch) {
        int j = ch * 64 + lane;
        float x = bxp[j * 3 + 0], y = bxp[j * 3 + 1], z = bxp[j * 3 + 2];
        float d2 = d2_exact(x, y, z, cx, cy, cz);
        bool hit = d2 < 0.04f;   // strict f32 compare
        unsigned long long m = __ballot(hit);
        int pos = have + __popcll(m & ((1ull << lane) - 1ull));
        if (hit && pos < NSAMPLE) sel_s[wave][pos] = j;
        have += __popcll(m);
    }
    __syncthreads();
    int nsel = have < NSAMPLE ? have : NSAMPLE;
    int first = sel_s[wave][0];   // centroid itself always hits -> nsel >= 1
    if (lane < NSAMPLE && lane >= nsel) sel_s[wave][lane] = first;
    __syncthreads();

    // ---- gather X = [rel_xyz(3) | features(32)] into LDS ------------------
    {
        int s = lane >> 1, h = lane & 1;
        int row = sel_s[wave][s];
        float* X = &bufA[wave][0];
        const float* fr = bfp + (size_t)row * NC + h * 16;
#pragma unroll
        for (int q = 0; q < 4; ++q) {
            float4 v = *(const float4*)(fr + q * 4);
            int base = s * XS + 3 + h * 16 + q * 4;
            X[base + 0] = v.x; X[base + 1] = v.y;
            X[base + 2] = v.z; X[base + 3] = v.w;
        }
        if (h == 0) {
            X[s * XS + 0] = __fsub_rn(bxp[row * 3 + 0], cx);
            X[s * XS + 1] = __fsub_rn(bxp[row * 3 + 1], cy);
            X[s * XS + 2] = __fsub_rn(bxp[row * 3 + 2], cz);
        }
    }
    __syncthreads();

    const int sg = lane >> 3;   // 0..7 -> samples sg*4 .. sg*4+3
    const int og = lane & 7;    // output-channel group

    // ---- layer 1: 35 -> 64 ------------------------------------------------
    {
        float acc[4][8];
#pragma unroll
        for (int j = 0; j < 4; ++j)
#pragma unroll
            for (int o = 0; o < 8; ++o) acc[j][o] = 0.f;
        const float* X = &bufA[wave][0];
        for (int c = 0; c < 35; ++c) {
            float xv[4];
#pragma unroll
            for (int j = 0; j < 4; ++j) xv[j] = X[(sg * 4 + j) * XS + c];
            const float* wr = w1 + c * 64 + og * 8;
            float4 wa = *(const float4*)(wr);
            float4 wb = *(const float4*)(wr + 4);
            float w8[8] = {wa.x, wa.y, wa.z, wa.w, wb.x, wb.y, wb.z, wb.w};
#pragma unroll
            for (int j = 0; j < 4; ++j)
#pragma unroll
                for (int o = 0; o < 8; ++o) acc[j][o] += xv[j] * w8[o];
        }
        float4 ba = *(const float4*)(b1 + og * 8);
        float4 bb = *(const float4*)(b1 + og * 8 + 4);
        float bias[8] = {ba.x, ba.y, ba.z, ba.w, bb.x, bb.y, bb.z, bb.w};
        float* H = &bufB[wave][0];
#pragma unroll
        for (int j = 0; j < 4; ++j)
#pragma unroll
            for (int o = 0; o < 8; ++o)
                H[(sg * 4 + j) * HS + og * 8 + o] = fmaxf(acc[j][o] + bias[o], 0.f);
    }
    __syncthreads();

    // ---- layer 2: 64 -> 64 ------------------------------------------------
    {
        float acc[4][8];
#pragma unroll
        for (int j = 0; j < 4; ++j)
#pragma unroll
            for (int o = 0; o < 8; ++o) acc[j][o] = 0.f;
        const float* H = &bufB[wave][0];
        for (int c = 0; c < 64; ++c) {
            float xv[4];
#pragma unroll
            for (int j = 0; j < 4; ++j) xv[j] = H[(sg * 4 + j) * HS + c];
            const float* wr = w2 + c * 64 + og * 8;
            float4 wa = *(const float4*)(wr);
            float4 wb = *(const float4*)(wr + 4);
            float w8[8] = {wa.x, wa.y, wa.z, wa.w, wb.x, wb.y, wb.z, wb.w};
#pragma unroll
            for (int j = 0; j < 4; ++j)
#pragma unroll
                for (int o = 0; o < 8; ++o) acc[j][o] += xv[j] * w8[o];
        }
        float4 ba = *(const float4*)(b2 + og * 8);
        float4 bb = *(const float4*)(b2 + og * 8 + 4);
        float bias[8] = {ba.x, ba.y, ba.z, ba.w, bb.x, bb.y, bb.z, bb.w};
        float* H2 = &bufA[wave][0];
#pragma unroll
        for (int j = 0; j < 4; ++j)
#pragma unroll
            for (int o = 0; o < 8; ++o)
                H2[(sg * 4 + j) * HS + og * 8 + o] = fmaxf(acc[j][o] + bias[o], 0.f);
    }
    __syncthreads();

    // ---- layer 3: 64 -> 128, maxpool over 32 samples ----------------------
    {
        float acc[4][16];
#pragma unroll
        for (int j = 0; j < 4; ++j)
#pragma unroll
            for (int o = 0; o < 16; ++o) acc[j][o] = 0.f;
        const float* H = &bufA[wave][0];
        for (int c = 0; c < 64; ++c) {
            float xv[4];
#pragma unroll
            for (int j = 0; j < 4; ++j) xv[j] = H[(sg * 4 + j) * HS + c];
            const float* wr = w3 + c * 128 + og * 16;
            float4 wq[4];
#pragma unroll
            for (int q = 0; q < 4; ++q) wq[q] = *(const float4*)(wr + q * 4);
            float w16[16] = {wq[0].x, wq[0].y, wq[0].z, wq[0].w,
                             wq[1].x, wq[1].y, wq[1].z, wq[1].w,
                             wq[2].x, wq[2].y, wq[2].z, wq[2].w,
                             wq[3].x, wq[3].y, wq[3].z, wq[3].w};
#pragma unroll
            for (int j = 0; j < 4; ++j)
#pragma unroll
                for (int o = 0; o < 16; ++o) acc[j][o] += xv[j] * w16[o];
        }
        // maxpool over the 4 local samples, then across sg via shuffles.
        float m[16];
#pragma unroll
        for (int o = 0; o < 16; ++o) {
            float t0 = fmaxf(acc[0][o], acc[1][o]);
            float t1 = fmaxf(acc[2][o], acc[3][o]);
            m[o] = fmaxf(t0, t1);
        }
#pragma unroll
        for (int off = 8; off <= 32; off <<= 1)
#pragma unroll
            for (int o = 0; o < 16; ++o) m[o] = fmaxf(m[o], __shfl_xor(m[o], off));
        // bias after max (exact: rn add is monotone), then relu, store
        if (sg == 0) {
            float4 bq[4];
#pragma unroll
            for (int q = 0; q < 4; ++q) bq[q] = *(const float4*)(b3 + og * 16 + q * 4);
            float bias[16] = {bq[0].x, bq[0].y, bq[0].z, bq[0].w,
                              bq[1].x, bq[1].y, bq[1].z, bq[1].w,
                              bq[2].x, bq[2].y, bq[2].z, bq[2].w,
                              bq[3].x, bq[3].y, bq[3].z, bq[3].w};
#pragma unroll
            for (int o = 0; o < 16; ++o) {
                float v = fmaxf(m[o] + bias[o], 0.f);
                out_feat[((size_t)b * 128 + og * 16 + o) * NPOINT + p] = v;
            }
        }
    }
}

// ---------------------------------------------------------------------------
extern "C" void kernel_launch(void* const* d_in, const int* in_sizes, int n_in,
                              void* d_out, int out_size, void* d_ws, size_t ws_size,
                              hipStream_t stream) {
    const float* xyz      = (const float*)d_in[0];
    const float* normal   = (const float*)d_in[1];
    const float* features = (const float*)d_in[2];
    const float* w1 = (const float*)d_in[3];
    const float* b1 = (const float*)d_in[4];
    const float* w2 = (const float*)d_in[5];
    const float* b2 = (const float*)d_in[6];
    const float* w3 = (const float*)d_in[7];
    const float* b3 = (const float*)d_in[8];

    float* out        = (float*)d_out;
    float* out_xyz    = out;                       // (8,1024,3)
    float* out_normal = out + NB * NPOINT * 3;     // (8,1024,3)
    float* out_feat   = out + 2 * NB * NPOINT * 3; // (8,128,1024)

    hipLaunchKernelGGL(fps_kernel, dim3(NB), dim3(FPS_T), 0, stream,
                       xyz, normal, out_xyz, out_normal);
    hipLaunchKernelGGL(group_mlp_kernel, dim3(NB * NPOINT / K2_WAVES),
                       dim3(64 * K2_WAVES), 0, stream,
                       xyz, features, w1, b1, w2, b2, w3, b3, out_xyz, out_feat);
}

// Round 3
// 1186.607 us; speedup vs baseline: 1.8839x; 1.0045x over previous
//
#include <hip/hip_runtime.h>

#define NB 8
#define NN 8192
#define NC 32
#define NPOINT 1024
#define NSAMPLE 32

// Exact round-to-nearest distance, no fma contraction: matches numpy
// ((dx*dx + dy*dy) + dz*dz) bitwise.
__device__ __forceinline__ float d2_exact(float ax, float ay, float az,
                                          float bx, float by, float bz) {
    float dx = __fsub_rn(ax, bx);
    float dy = __fsub_rn(ay, by);
    float dz = __fsub_rn(az, bz);
    return __fadd_rn(__fadd_rn(__fmul_rn(dx, dx), __fmul_rn(dy, dy)),
                     __fmul_rn(dz, dz));
}

// ---------------------------------------------------------------------------
// Kernel 1: furthest point sampling, one block per batch, 256 threads
// (4 waves, 1 wave/SIMD), 32 points/thread in registers.
//
// __launch_bounds__(256, 1): min 1 wave/EU -> VGPR budget up to 512/wave.
// Without this the compiler capped at 84 VGPRs and spilled the 128-register
// px/py/pz/dist arrays to scratch (720 MB HBM FETCH per dispatch, round 2).
//
// Argmax strategy: key = (f32_bits(dist) << 32) | ~p. dist >= 0 so bits are
// monotone; max(key) = max dist with ties -> min p (numpy first-occurrence).
// Wave reduce via DPP; cross-wave via 4 LDS slots + ONE barrier/iter (parity
// double-buffer); winner coords via uniform scalar global load.
// ---------------------------------------------------------------------------
#define FPS_T 256
#define FPS_K (NN / FPS_T)   // 32

__device__ __forceinline__ unsigned long long kmax64(unsigned long long a,
                                                     unsigned long long b) {
    return a > b ? a : b;
}

template <int CTRL, int RM>
__device__ __forceinline__ unsigned long long dpp_k(unsigned long long k) {
    unsigned hi = (unsigned)__builtin_amdgcn_update_dpp(
        0, (int)(k >> 32), CTRL, RM, 0xf, true);
    unsigned lo = (unsigned)__builtin_amdgcn_update_dpp(
        0, (int)(k & 0xffffffffULL), CTRL, RM, 0xf, true);
    return ((unsigned long long)hi << 32) | lo;
}

__global__ __launch_bounds__(FPS_T, 1) void fps_kernel(
    const float* __restrict__ xyz, const float* __restrict__ normal,
    float* __restrict__ out_xyz, float* __restrict__ out_normal) {
    const int b = blockIdx.x;
    const float* bx = xyz + (size_t)b * NN * 3;
    const int tid = threadIdx.x;
    const int lane = tid & 63;
    const int wave = tid >> 6;   // 0..3

    __shared__ unsigned long long redk[2][4];
    __shared__ int sel_hist[NPOINT];

    float px[FPS_K], py[FPS_K], pz[FPS_K], dist[FPS_K];
#pragma unroll
    for (int k = 0; k < FPS_K; ++k) {
        int p = tid + k * FPS_T;
        px[k] = bx[p * 3 + 0];
        py[k] = bx[p * 3 + 1];
        pz[k] = bx[p * 3 + 2];
        dist[k] = 1e10f;
    }

    int cur = 0;
    float lx = bx[0], ly = bx[1], lz = bx[2];

    for (int it = 0; it < NPOINT; ++it) {
        const int par = it & 1;
        if (tid == 0) sel_hist[it] = cur;

        // update dists with current point; track per-thread argmax as k-index
        float bv = -1.0f;
        int bk = 0;
#pragma unroll
        for (int k = 0; k < FPS_K; ++k) {
            float d = d2_exact(px[k], py[k], pz[k], lx, ly, lz);
            float nd = fminf(dist[k], d);
            dist[k] = nd;
            bool gt = nd > bv;          // strict >: keeps lowest p on ties
            bv = gt ? nd : bv;
            bk = gt ? k : bk;           // k is an inline const per unroll step
        }
        int bp = tid + (bk << 8);       // global point index (FPS_T == 256)
        unsigned long long key =
            ((unsigned long long)__float_as_uint(bv) << 32) |
            (unsigned)(~bp);

        // wave-wide max via DPP: row_shr 1/2/4/8, bcast15, bcast31.
        // Zero-fill is safe: key 0 => dist +0.0, ~p=0 -> never beats a real key.
        key = kmax64(key, dpp_k<0x111, 0xf>(key));
        key = kmax64(key, dpp_k<0x112, 0xf>(key));
        key = kmax64(key, dpp_k<0x114, 0xf>(key));
        key = kmax64(key, dpp_k<0x118, 0xf>(key));
        key = kmax64(key, dpp_k<0x142, 0xa>(key));
        key = kmax64(key, dpp_k<0x143, 0xc>(key));
        // lane 63 holds the wave max
        if (lane == 63) redk[par][wave] = key;
        __syncthreads();

        unsigned long long g =
            kmax64(kmax64(redk[par][0], redk[par][1]),
                   kmax64(redk[par][2], redk[par][3]));
        int p = (int)(~(unsigned)(g & 0xffffffffULL));
        p = __builtin_amdgcn_readfirstlane(p);   // uniform -> scalar loads
        const float* lp = bx + 3 * (size_t)p;
        lx = lp[0]; ly = lp[1]; lz = lp[2];
        cur = p;
    }
    __syncthreads();

    // gather new_xyz / new_normal
    const float* bn = normal + (size_t)b * NN * 3;
    for (int t = tid; t < NPOINT; t += FPS_T) {
        int i = sel_hist[t];
        size_t o = ((size_t)b * NPOINT + t) * 3;
        out_xyz[o + 0] = bx[i * 3 + 0];
        out_xyz[o + 1] = bx[i * 3 + 1];
        out_xyz[o + 2] = bx[i * 3 + 2];
        out_normal[o + 0] = bn[i * 3 + 0];
        out_normal[o + 1] = bn[i * 3 + 1];
        out_normal[o + 2] = bn[i * 3 + 2];
    }
}

// ---------------------------------------------------------------------------
// Kernel 2: ball query + gather + 3-layer MLP + maxpool, one wave per
// centroid, 2 waves (128 threads) per block (static LDS < 64 KB).
// ---------------------------------------------------------------------------
#define K2_WAVES 2
#define XS 37   // X row stride (35 cols + pad)
#define HS 65   // H row stride (64 cols + pad)

__global__ __launch_bounds__(64 * K2_WAVES) void group_mlp_kernel(
    const float* __restrict__ xyz, const float* __restrict__ features,
    const float* __restrict__ w1, const float* __restrict__ b1,
    const float* __restrict__ w2, const float* __restrict__ b2,
    const float* __restrict__ w3, const float* __restrict__ b3,
    const float* __restrict__ new_xyz, float* __restrict__ out_feat) {
    const int wave = threadIdx.x >> 6;
    const int lane = threadIdx.x & 63;
    const int g = blockIdx.x * K2_WAVES + wave;   // centroid id, 0..8191
    const int b = g >> 10;
    const int p = g & 1023;
    const float* bxp = xyz + (size_t)b * NN * 3;
    const float* bfp = features + (size_t)b * NN * NC;

    __shared__ int sel_s[K2_WAVES][NSAMPLE];
    __shared__ float bufA[K2_WAVES][32 * HS];   // X (stride XS) then H2 (stride HS)
    __shared__ float bufB[K2_WAVES][32 * HS];   // H1

    const float cx = new_xyz[(size_t)g * 3 + 0];
    const float cy = new_xyz[(size_t)g * 3 + 1];
    const float cz = new_xyz[(size_t)g * 3 + 2];

    // ---- ball query: first NSAMPLE hits in ascending index order ----------
    int have = 0;
    for (int ch = 0; ch < NN / 64 && have < NSAMPLE; ++ch) {
        int j = ch * 64 + lane;
        float x = bxp[j * 3 + 0], y = bxp[j * 3 + 1], z = bxp[j * 3 + 2];
        float d2 = d2_exact(x, y, z, cx, cy, cz);
        bool hit = d2 < 0.04f;   // strict f32 compare
        unsigned long long m = __ballot(hit);
        int pos = have + __popcll(m & ((1ull << lane) - 1ull));
        if (hit && pos < NSAMPLE) sel_s[wave][pos] = j;
        have += __popcll(m);
    }
    __syncthreads();
    int nsel = have < NSAMPLE ? have : NSAMPLE;
    int first = sel_s[wave][0];   // centroid itself always hits -> nsel >= 1
    if (lane < NSAMPLE && lane >= nsel) sel_s[wave][lane] = first;
    __syncthreads();

    // ---- gather X = [rel_xyz(3) | features(32)] into LDS ------------------
    {
        int s = lane >> 1, h = lane & 1;
        int row = sel_s[wave][s];
        float* X = &bufA[wave][0];
        const float* fr = bfp + (size_t)row * NC + h * 16;
#pragma unroll
        for (int q = 0; q < 4; ++q) {
            float4 v = *(const float4*)(fr + q * 4);
            int base = s * XS + 3 + h * 16 + q * 4;
            X[base + 0] = v.x; X[base + 1] = v.y;
            X[base + 2] = v.z; X[base + 3] = v.w;
        }
        if (h == 0) {
            X[s * XS + 0] = __fsub_rn(bxp[row * 3 + 0], cx);
            X[s * XS + 1] = __fsub_rn(bxp[row * 3 + 1], cy);
            X[s * XS + 2] = __fsub_rn(bxp[row * 3 + 2], cz);
        }
    }
    __syncthreads();

    const int sg = lane >> 3;   // 0..7 -> samples sg*4 .. sg*4+3
    const int og = lane & 7;    // output-channel group

    // ---- layer 1: 35 -> 64 ------------------------------------------------
    {
        float acc[4][8];
#pragma unroll
        for (int j = 0; j < 4; ++j)
#pragma unroll
            for (int o = 0; o < 8; ++o) acc[j][o] = 0.f;
        const float* X = &bufA[wave][0];
        for (int c = 0; c < 35; ++c) {
            float xv[4];
#pragma unroll
            for (int j = 0; j < 4; ++j) xv[j] = X[(sg * 4 + j) * XS + c];
            const float* wr = w1 + c * 64 + og * 8;
            float4 wa = *(const float4*)(wr);
            float4 wb = *(const float4*)(wr + 4);
            float w8[8] = {wa.x, wa.y, wa.z, wa.w, wb.x, wb.y, wb.z, wb.w};
#pragma unroll
            for (int j = 0; j < 4; ++j)
#pragma unroll
                for (int o = 0; o < 8; ++o) acc[j][o] += xv[j] * w8[o];
        }
        float4 ba = *(const float4*)(b1 + og * 8);
        float4 bb = *(const float4*)(b1 + og * 8 + 4);
        float bias[8] = {ba.x, ba.y, ba.z, ba.w, bb.x, bb.y, bb.z, bb.w};
        float* H = &bufB[wave][0];
#pragma unroll
        for (int j = 0; j < 4; ++j)
#pragma unroll
            for (int o = 0; o < 8; ++o)
                H[(sg * 4 + j) * HS + og * 8 + o] = fmaxf(acc[j][o] + bias[o], 0.f);
    }
    __syncthreads();

    // ---- layer 2: 64 -> 64 ------------------------------------------------
    {
        float acc[4][8];
#pragma unroll
        for (int j = 0; j < 4; ++j)
#pragma unroll
            for (int o = 0; o < 8; ++o) acc[j][o] = 0.f;
        const float* H = &bufB[wave][0];
        for (int c = 0; c < 64; ++c) {
            float xv[4];
#pragma unroll
            for (int j = 0; j < 4; ++j) xv[j] = H[(sg * 4 + j) * HS + c];
            const float* wr = w2 + c * 64 + og * 8;
            float4 wa = *(const float4*)(wr);
            float4 wb = *(const float4*)(wr + 4);
            float w8[8] = {wa.x, wa.y, wa.z, wa.w, wb.x, wb.y, wb.z, wb.w};
#pragma unroll
            for (int j = 0; j < 4; ++j)
#pragma unroll
                for (int o = 0; o < 8; ++o) acc[j][o] += xv[j] * w8[o];
        }
        float4 ba = *(const float4*)(b2 + og * 8);
        float4 bb = *(const float4*)(b2 + og * 8 + 4);
        float bias[8] = {ba.x, ba.y, ba.z, ba.w, bb.x, bb.y, bb.z, bb.w};
        float* H2 = &bufA[wave][0];
#pragma unroll
        for (int j = 0; j < 4; ++j)
#pragma unroll
            for (int o = 0; o < 8; ++o)
                H2[(sg * 4 + j) * HS + og * 8 + o] = fmaxf(acc[j][o] + bias[o], 0.f);
    }
    __syncthreads();

    // ---- layer 3: 64 -> 128, maxpool over 32 samples ----------------------
    {
        float acc[4][16];
#pragma unroll
        for (int j = 0; j < 4; ++j)
#pragma unroll
            for (int o = 0; o < 16; ++o) acc[j][o] = 0.f;
        const float* H = &bufA[wave][0];
        for (int c = 0; c < 64; ++c) {
            float xv[4];
#pragma unroll
            for (int j = 0; j < 4; ++j) xv[j] = H[(sg * 4 + j) * HS + c];
            const float* wr = w3 + c * 128 + og * 16;
            float4 wq[4];
#pragma unroll
            for (int q = 0; q < 4; ++q) wq[q] = *(const float4*)(wr + q * 4);
            float w16[16] = {wq[0].x, wq[0].y, wq[0].z, wq[0].w,
                             wq[1].x, wq[1].y, wq[1].z, wq[1].w,
                             wq[2].x, wq[2].y, wq[2].z, wq[2].w,
                             wq[3].x, wq[3].y, wq[3].z, wq[3].w};
#pragma unroll
            for (int j = 0; j < 4; ++j)
#pragma unroll
                for (int o = 0; o < 16; ++o) acc[j][o] += xv[j] * w16[o];
        }
        // maxpool over the 4 local samples, then across sg via shuffles.
        float m[16];
#pragma unroll
        for (int o = 0; o < 16; ++o) {
            float t0 = fmaxf(acc[0][o], acc[1][o]);
            float t1 = fmaxf(acc[2][o], acc[3][o]);
            m[o] = fmaxf(t0, t1);
        }
#pragma unroll
        for (int off = 8; off <= 32; off <<= 1)
#pragma unroll
            for (int o = 0; o < 16; ++o) m[o] = fmaxf(m[o], __shfl_xor(m[o], off));
        // bias after max (exact: rn add is monotone), then relu, store
        if (sg == 0) {
            float4 bq[4];
#pragma unroll
            for (int q = 0; q < 4; ++q) bq[q] = *(const float4*)(b3 + og * 16 + q * 4);
            float bias[16] = {bq[0].x, bq[0].y, bq[0].z, bq[0].w,
                              bq[1].x, bq[1].y, bq[1].z, bq[1].w,
                              bq[2].x, bq[2].y, bq[2].z, bq[2].w,
                              bq[3].x, bq[3].y, bq[3].z, bq[3].w};
#pragma unroll
            for (int o = 0; o < 16; ++o) {
                float v = fmaxf(m[o] + bias[o], 0.f);
                out_feat[((size_t)b * 128 + og * 16 + o) * NPOINT + p] = v;
            }
        }
    }
}

// ---------------------------------------------------------------------------
extern "C" void kernel_launch(void* const* d_in, const int* in_sizes, int n_in,
                              void* d_out, int out_size, void* d_ws, size_t ws_size,
                              hipStream_t stream) {
    const float* xyz      = (const float*)d_in[0];
    const float* normal   = (const float*)d_in[1];
    const float* features = (const float*)d_in[2];
    const float* w1 = (const float*)d_in[3];
    const float* b1 = (const float*)d_in[4];
    const float* w2 = (const float*)d_in[5];
    const float* b2 = (const float*)d_in[6];
    const float* w3 = (const float*)d_in[7];
    const float* b3 = (const float*)d_in[8];

    float* out        = (float*)d_out;
    float* out_xyz    = out;                       // (8,1024,3)
    float* out_normal = out + NB * NPOINT * 3;     // (8,1024,3)
    float* out_feat   = out + 2 * NB * NPOINT * 3; // (8,128,1024)

    hipLaunchKernelGGL(fps_kernel, dim3(NB), dim3(FPS_T), 0, stream,
                       xyz, normal, out_xyz, out_normal);
    hipLaunchKernelGGL(group_mlp_kernel, dim3(NB * NPOINT / K2_WAVES),
                       dim3(64 * K2_WAVES), 0, stream,
                       xyz, features, w1, b1, w2, b2, w3, b3, out_xyz, out_feat);
}

// Round 4
// 1184.470 us; speedup vs baseline: 1.8873x; 1.0018x over previous
//
#include <hip/hip_runtime.h>

#define NB 8
#define NN 8192
#define NC 32
#define NPOINT 1024
#define NSAMPLE 32

// Exact round-to-nearest distance, no fma contraction: matches numpy
// ((dx*dx + dy*dy) + dz*dz) bitwise.
__device__ __forceinline__ float d2_exact(float ax, float ay, float az,
                                          float bx, float by, float bz) {
    float dx = __fsub_rn(ax, bx);
    float dy = __fsub_rn(ay, by);
    float dz = __fsub_rn(az, bz);
    return __fadd_rn(__fadd_rn(__fmul_rn(dx, dx), __fmul_rn(dy, dy)),
                     __fmul_rn(dz, dz));
}

// ---------------------------------------------------------------------------
// Kernel 1: furthest point sampling, one block per batch, 256 threads
// (4 waves, 1 wave/SIMD), 32 points/thread in registers.
//
// Round-3 lesson: the compiler SANK the coordinate loads into the 1024-iter
// loop (re-loading 96 floats/thread/iter from L2) instead of keeping them in
// VGPRs — VGPR_Count stayed 84 despite __launch_bounds__(256,1). The empty
// asm below makes the loaded values opaque, forcing them to stay register-
// resident across the whole selection loop.
//
// Argmax strategy: key = (f32_bits(dist) << 32) | ~p. dist >= 0 so bits are
// monotone; max(key) = max dist with ties -> min p (numpy first-occurrence).
// Wave reduce via DPP; cross-wave via 4 LDS slots + ONE barrier/iter (parity
// double-buffer); winner coords via uniform scalar global load.
// ---------------------------------------------------------------------------
#define FPS_T 256
#define FPS_K (NN / FPS_T)   // 32

__device__ __forceinline__ unsigned long long kmax64(unsigned long long a,
                                                     unsigned long long b) {
    return a > b ? a : b;
}

template <int CTRL, int RM>
__device__ __forceinline__ unsigned long long dpp_k(unsigned long long k) {
    unsigned hi = (unsigned)__builtin_amdgcn_update_dpp(
        0, (int)(k >> 32), CTRL, RM, 0xf, true);
    unsigned lo = (unsigned)__builtin_amdgcn_update_dpp(
        0, (int)(k & 0xffffffffULL), CTRL, RM, 0xf, true);
    return ((unsigned long long)hi << 32) | lo;
}

__global__ __launch_bounds__(FPS_T, 1) void fps_kernel(
    const float* __restrict__ xyz, const float* __restrict__ normal,
    float* __restrict__ out_xyz, float* __restrict__ out_normal) {
    const int b = blockIdx.x;
    const float* bx = xyz + (size_t)b * NN * 3;
    const int tid = threadIdx.x;
    const int lane = tid & 63;
    const int wave = tid >> 6;   // 0..3

    __shared__ unsigned long long redk[2][4];
    __shared__ int sel_hist[NPOINT];

    float px[FPS_K], py[FPS_K], pz[FPS_K], dist[FPS_K];
#pragma unroll
    for (int k = 0; k < FPS_K; ++k) {
        int p = tid + k * FPS_T;
        px[k] = bx[p * 3 + 0];
        py[k] = bx[p * 3 + 1];
        pz[k] = bx[p * 3 + 2];
        dist[k] = 1e10f;
    }
    // Pin the coordinate arrays in VGPRs: opaque asm prevents the compiler
    // from sinking/rematerializing the global loads inside the hot loop.
#pragma unroll
    for (int k = 0; k < FPS_K; ++k) {
        asm volatile("" : "+v"(px[k]), "+v"(py[k]), "+v"(pz[k]));
    }

    int cur = 0;
    float lx = bx[0], ly = bx[1], lz = bx[2];

    for (int it = 0; it < NPOINT; ++it) {
        const int par = it & 1;
        if (tid == 0) sel_hist[it] = cur;

        // update dists with current point; track per-thread argmax as k-index
        float bv = -1.0f;
        int bk = 0;
#pragma unroll
        for (int k = 0; k < FPS_K; ++k) {
            float d = d2_exact(px[k], py[k], pz[k], lx, ly, lz);
            float nd = fminf(dist[k], d);
            dist[k] = nd;
            bool gt = nd > bv;          // strict >: keeps lowest p on ties
            bv = gt ? nd : bv;
            bk = gt ? k : bk;           // k is an inline const per unroll step
        }
        int bp = tid + (bk << 8);       // global point index (FPS_T == 256)
        unsigned long long key =
            ((unsigned long long)__float_as_uint(bv) << 32) |
            (unsigned)(~bp);

        // wave-wide max via DPP: row_shr 1/2/4/8, bcast15, bcast31.
        // Zero-fill is safe: key 0 => dist +0.0, ~p=0 -> never beats a real key.
        key = kmax64(key, dpp_k<0x111, 0xf>(key));
        key = kmax64(key, dpp_k<0x112, 0xf>(key));
        key = kmax64(key, dpp_k<0x114, 0xf>(key));
        key = kmax64(key, dpp_k<0x118, 0xf>(key));
        key = kmax64(key, dpp_k<0x142, 0xa>(key));
        key = kmax64(key, dpp_k<0x143, 0xc>(key));
        // lane 63 holds the wave max
        if (lane == 63) redk[par][wave] = key;
        __syncthreads();

        unsigned long long g =
            kmax64(kmax64(redk[par][0], redk[par][1]),
                   kmax64(redk[par][2], redk[par][3]));
        int p = (int)(~(unsigned)(g & 0xffffffffULL));
        p = __builtin_amdgcn_readfirstlane(p);   // uniform -> scalar loads
        const float* lp = bx + 3 * (size_t)p;
        lx = lp[0]; ly = lp[1]; lz = lp[2];
        cur = p;
    }
    __syncthreads();

    // gather new_xyz / new_normal
    const float* bn = normal + (size_t)b * NN * 3;
    for (int t = tid; t < NPOINT; t += FPS_T) {
        int i = sel_hist[t];
        size_t o = ((size_t)b * NPOINT + t) * 3;
        out_xyz[o + 0] = bx[i * 3 + 0];
        out_xyz[o + 1] = bx[i * 3 + 1];
        out_xyz[o + 2] = bx[i * 3 + 2];
        out_normal[o + 0] = bn[i * 3 + 0];
        out_normal[o + 1] = bn[i * 3 + 1];
        out_normal[o + 2] = bn[i * 3 + 2];
    }
}

// ---------------------------------------------------------------------------
// Kernel 2: ball query + gather + 3-layer MLP + maxpool, one wave per
// centroid, 2 waves (128 threads) per block (static LDS < 64 KB).
// ---------------------------------------------------------------------------
#define K2_WAVES 2
#define XS 37   // X row stride (35 cols + pad)
#define HS 65   // H row stride (64 cols + pad)

__global__ __launch_bounds__(64 * K2_WAVES) void group_mlp_kernel(
    const float* __restrict__ xyz, const float* __restrict__ features,
    const float* __restrict__ w1, const float* __restrict__ b1,
    const float* __restrict__ w2, const float* __restrict__ b2,
    const float* __restrict__ w3, const float* __restrict__ b3,
    const float* __restrict__ new_xyz, float* __restrict__ out_feat) {
    const int wave = threadIdx.x >> 6;
    const int lane = threadIdx.x & 63;
    const int g = blockIdx.x * K2_WAVES + wave;   // centroid id, 0..8191
    const int b = g >> 10;
    const int p = g & 1023;
    const float* bxp = xyz + (size_t)b * NN * 3;
    const float* bfp = features + (size_t)b * NN * NC;

    __shared__ int sel_s[K2_WAVES][NSAMPLE];
    __shared__ float bufA[K2_WAVES][32 * HS];   // X (stride XS) then H2 (stride HS)
    __shared__ float bufB[K2_WAVES][32 * HS];   // H1

    const float cx = new_xyz[(size_t)g * 3 + 0];
    const float cy = new_xyz[(size_t)g * 3 + 1];
    const float cz = new_xyz[(size_t)g * 3 + 2];

    // ---- ball query: first NSAMPLE hits in ascending index order ----------
    int have = 0;
    for (int ch = 0; ch < NN / 64 && have < NSAMPLE; ++ch) {
        int j = ch * 64 + lane;
        float x = bxp[j * 3 + 0], y = bxp[j * 3 + 1], z = bxp[j * 3 + 2];
        float d2 = d2_exact(x, y, z, cx, cy, cz);
        bool hit = d2 < 0.04f;   // strict f32 compare
        unsigned long long m = __ballot(hit);
        int pos = have + __popcll(m & ((1ull << lane) - 1ull));
        if (hit && pos < NSAMPLE) sel_s[wave][pos] = j;
        have += __popcll(m);
    }
    __syncthreads();
    int nsel = have < NSAMPLE ? have : NSAMPLE;
    int first = sel_s[wave][0];   // centroid itself always hits -> nsel >= 1
    if (lane < NSAMPLE && lane >= nsel) sel_s[wave][lane] = first;
    __syncthreads();

    // ---- gather X = [rel_xyz(3) | features(32)] into LDS ------------------
    {
        int s = lane >> 1, h = lane & 1;
        int row = sel_s[wave][s];
        float* X = &bufA[wave][0];
        const float* fr = bfp + (size_t)row * NC + h * 16;
#pragma unroll
        for (int q = 0; q < 4; ++q) {
            float4 v = *(const float4*)(fr + q * 4);
            int base = s * XS + 3 + h * 16 + q * 4;
            X[base + 0] = v.x; X[base + 1] = v.y;
            X[base + 2] = v.z; X[base + 3] = v.w;
        }
        if (h == 0) {
            X[s * XS + 0] = __fsub_rn(bxp[row * 3 + 0], cx);
            X[s * XS + 1] = __fsub_rn(bxp[row * 3 + 1], cy);
            X[s * XS + 2] = __fsub_rn(bxp[row * 3 + 2], cz);
        }
    }
    __syncthreads();

    const int sg = lane >> 3;   // 0..7 -> samples sg*4 .. sg*4+3
    const int og = lane & 7;    // output-channel group

    // ---- layer 1: 35 -> 64 ------------------------------------------------
    {
        float acc[4][8];
#pragma unroll
        for (int j = 0; j < 4; ++j)
#pragma unroll
            for (int o = 0; o < 8; ++o) acc[j][o] = 0.f;
        const float* X = &bufA[wave][0];
        for (int c = 0; c < 35; ++c) {
            float xv[4];
#pragma unroll
            for (int j = 0; j < 4; ++j) xv[j] = X[(sg * 4 + j) * XS + c];
            const float* wr = w1 + c * 64 + og * 8;
            float4 wa = *(const float4*)(wr);
            float4 wb = *(const float4*)(wr + 4);
            float w8[8] = {wa.x, wa.y, wa.z, wa.w, wb.x, wb.y, wb.z, wb.w};
#pragma unroll
            for (int j = 0; j < 4; ++j)
#pragma unroll
                for (int o = 0; o < 8; ++o) acc[j][o] += xv[j] * w8[o];
        }
        float4 ba = *(const float4*)(b1 + og * 8);
        float4 bb = *(const float4*)(b1 + og * 8 + 4);
        float bias[8] = {ba.x, ba.y, ba.z, ba.w, bb.x, bb.y, bb.z, bb.w};
        float* H = &bufB[wave][0];
#pragma unroll
        for (int j = 0; j < 4; ++j)
#pragma unroll
            for (int o = 0; o < 8; ++o)
                H[(sg * 4 + j) * HS + og * 8 + o] = fmaxf(acc[j][o] + bias[o], 0.f);
    }
    __syncthreads();

    // ---- layer 2: 64 -> 64 ------------------------------------------------
    {
        float acc[4][8];
#pragma unroll
        for (int j = 0; j < 4; ++j)
#pragma unroll
            for (int o = 0; o < 8; ++o) acc[j][o] = 0.f;
        const float* H = &bufB[wave][0];
        for (int c = 0; c < 64; ++c) {
            float xv[4];
#pragma unroll
            for (int j = 0; j < 4; ++j) xv[j] = H[(sg * 4 + j) * HS + c];
            const float* wr = w2 + c * 64 + og * 8;
            float4 wa = *(const float4*)(wr);
            float4 wb = *(const float4*)(wr + 4);
            float w8[8] = {wa.x, wa.y, wa.z, wa.w, wb.x, wb.y, wb.z, wb.w};
#pragma unroll
            for (int j = 0; j < 4; ++j)
#pragma unroll
                for (int o = 0; o < 8; ++o) acc[j][o] += xv[j] * w8[o];
        }
        float4 ba = *(const float4*)(b2 + og * 8);
        float4 bb = *(const float4*)(b2 + og * 8 + 4);
        float bias[8] = {ba.x, ba.y, ba.z, ba.w, bb.x, bb.y, bb.z, bb.w};
        float* H2 = &bufA[wave][0];
#pragma unroll
        for (int j = 0; j < 4; ++j)
#pragma unroll
            for (int o = 0; o < 8; ++o)
                H2[(sg * 4 + j) * HS + og * 8 + o] = fmaxf(acc[j][o] + bias[o], 0.f);
    }
    __syncthreads();

    // ---- layer 3: 64 -> 128, maxpool over 32 samples ----------------------
    {
        float acc[4][16];
#pragma unroll
        for (int j = 0; j < 4; ++j)
#pragma unroll
            for (int o = 0; o < 16; ++o) acc[j][o] = 0.f;
        const float* H = &bufA[wave][0];
        for (int c = 0; c < 64; ++c) {
            float xv[4];
#pragma unroll
            for (int j = 0; j < 4; ++j) xv[j] = H[(sg * 4 + j) * HS + c];
            const float* wr = w3 + c * 128 + og * 16;
            float4 wq[4];
#pragma unroll
            for (int q = 0; q < 4; ++q) wq[q] = *(const float4*)(wr + q * 4);
            float w16[16] = {wq[0].x, wq[0].y, wq[0].z, wq[0].w,
                             wq[1].x, wq[1].y, wq[1].z, wq[1].w,
                             wq[2].x, wq[2].y, wq[2].z, wq[2].w,
                             wq[3].x, wq[3].y, wq[3].z, wq[3].w};
#pragma unroll
            for (int j = 0; j < 4; ++j)
#pragma unroll
                for (int o = 0; o < 16; ++o) acc[j][o] += xv[j] * w16[o];
        }
        // maxpool over the 4 local samples, then across sg via shuffles.
        float m[16];
#pragma unroll
        for (int o = 0; o < 16; ++o) {
            float t0 = fmaxf(acc[0][o], acc[1][o]);
            float t1 = fmaxf(acc[2][o], acc[3][o]);
            m[o] = fmaxf(t0, t1);
        }
#pragma unroll
        for (int off = 8; off <= 32; off <<= 1)
#pragma unroll
            for (int o = 0; o < 16; ++o) m[o] = fmaxf(m[o], __shfl_xor(m[o], off));
        // bias after max (exact: rn add is monotone), then relu, store
        if (sg == 0) {
            float4 bq[4];
#pragma unroll
            for (int q = 0; q < 4; ++q) bq[q] = *(const float4*)(b3 + og * 16 + q * 4);
            float bias[16] = {bq[0].x, bq[0].y, bq[0].z, bq[0].w,
                              bq[1].x, bq[1].y, bq[1].z, bq[1].w,
                              bq[2].x, bq[2].y, bq[2].z, bq[2].w,
                              bq[3].x, bq[3].y, bq[3].z, bq[3].w};
#pragma unroll
            for (int o = 0; o < 16; ++o) {
                float v = fmaxf(m[o] + bias[o], 0.f);
                out_feat[((size_t)b * 128 + og * 16 + o) * NPOINT + p] = v;
            }
        }
    }
}

// ---------------------------------------------------------------------------
extern "C" void kernel_launch(void* const* d_in, const int* in_sizes, int n_in,
                              void* d_out, int out_size, void* d_ws, size_t ws_size,
                              hipStream_t stream) {
    const float* xyz      = (const float*)d_in[0];
    const float* normal   = (const float*)d_in[1];
    const float* features = (const float*)d_in[2];
    const float* w1 = (const float*)d_in[3];
    const float* b1 = (const float*)d_in[4];
    const float* w2 = (const float*)d_in[5];
    const float* b2 = (const float*)d_in[6];
    const float* w3 = (const float*)d_in[7];
    const float* b3 = (const float*)d_in[8];

    float* out        = (float*)d_out;
    float* out_xyz    = out;                       // (8,1024,3)
    float* out_normal = out + NB * NPOINT * 3;     // (8,1024,3)
    float* out_feat   = out + 2 * NB * NPOINT * 3; // (8,128,1024)

    hipLaunchKernelGGL(fps_kernel, dim3(NB), dim3(FPS_T), 0, stream,
                       xyz, normal, out_xyz, out_normal);
    hipLaunchKernelGGL(group_mlp_kernel, dim3(NB * NPOINT / K2_WAVES),
                       dim3(64 * K2_WAVES), 0, stream,
                       xyz, features, w1, b1, w2, b2, w3, b3, out_xyz, out_feat);
}